// Round 9
// baseline (268.390 us; speedup 1.0000x reference)
//
#include <hip/hip_runtime.h>

#define NN      1024      // num nodes
#define IN_DIM  16
#define HID     32
#define OUT_DIM 256
#define NE      8192      // edges (without self loops)
#define FDIM    (NN*HID)  // 32768
#define F4      (FDIM/4)  // 8192
#define F8      (FDIM/8)  // 4096
#define MAXNB   48        // staged rows per node (self + neighbors)

typedef float f4 __attribute__((ext_vector_type(4)));

// ---------------- fused CSR build: one block, all in LDS ----------------
__global__ void __launch_bounds__(1024) csr_k(
    const int* __restrict__ row, const int* __restrict__ col,
    float* __restrict__ deg_g, int* __restrict__ off_g,
    int* __restrict__ nrow, float* __restrict__ nw)
{
    __shared__ float degs[NN];
    __shared__ int   curs[NN];
    __shared__ int   scan[NN];
    const int t = threadIdx.x;
    degs[t] = 1.f;                       // self loop
    __syncthreads();
    for (int e = t; e < NE; e += 1024) atomicAdd(&degs[col[e]], 1.f);
    __syncthreads();
    int c = (int)degs[t] - 1;            // in-edges excluding self loop
    scan[t] = c;
    __syncthreads();
    for (int d = 1; d < 1024; d <<= 1) {
        int v = (t >= d) ? scan[t - d] : 0;
        __syncthreads();
        scan[t] += v;
        __syncthreads();
    }
    int excl = scan[t] - c;
    curs[t] = excl;
    off_g[t] = excl;
    deg_g[t] = degs[t];
    __syncthreads();
    for (int e = t; e < NE; e += 1024) {
        int r = row[e], cc = col[e];
        int slot = atomicAdd(&curs[cc], 1);
        nrow[slot] = r;
        nw[slot] = rsqrtf(degs[r] * degs[cc]);
    }
}

// ---------------- gather-form GCN conv: one block per node, LDS-staged rows ----
// EPI: 0 -> OUT = tot ; 1 -> OUT = tot + relu(RES) ; 2 -> OUT = relu(tot + relu(RES))
template<int K, int RELU_IN, int EPI>
__global__ void __launch_bounds__(256) conv_k(
    const float* __restrict__ IN, const float* __restrict__ RES,
    const float* __restrict__ W, const float* __restrict__ bias,
    const float* __restrict__ deg, const int* __restrict__ off,
    const int* __restrict__ nrow, const float* __restrict__ nw,
    float* __restrict__ OUT)
{
    const int n = blockIdx.x;
    const int tid = threadIdx.x;
    const int s = tid >> 5, f = tid & 31;
    __shared__ float rows[MAXNB][K + 4];
    __shared__ float part[8][33];
    const int base = off[n];
    const int cnt = (int)deg[n] - 1;         // neighbors excluding self
    const int tot = cnt + 1;
    const int stg = tot < MAXNB ? tot : MAXNB;
    const int vecs = K / 4;
    for (int idx = tid; idx < stg * vecs; idx += 256) {
        int j = idx / vecs, q = idx - j * vecs;
        int r = (j == 0) ? n : nrow[base + j - 1];
        float4 val = *reinterpret_cast<const float4*>(IN + r * K + q * 4);
        if (RELU_IN) {
            val.x = fmaxf(val.x, 0.f); val.y = fmaxf(val.y, 0.f);
            val.z = fmaxf(val.z, 0.f); val.w = fmaxf(val.w, 0.f);
        }
        rows[j][q * 4 + 0] = val.x; rows[j][q * 4 + 1] = val.y;
        rows[j][q * 4 + 2] = val.z; rows[j][q * 4 + 3] = val.w;
    }
    __syncthreads();
    float acc = 0.f;
    for (int j = s; j < tot; j += 8) {
        float w = (j == 0) ? (1.0f / deg[n]) : nw[base + j - 1];
        float hw = 0.f;
        if (j < MAXNB) {
            #pragma unroll
            for (int k = 0; k < K; ++k)
                hw = fmaf(rows[j][k], W[k * HID + f], hw);
        } else {
            const float* inr = IN + nrow[base + j - 1] * K;
            #pragma unroll
            for (int k = 0; k < K; ++k) {
                float t = inr[k];
                if (RELU_IN) t = fmaxf(t, 0.f);
                hw = fmaf(t, W[k * HID + f], hw);
            }
        }
        acc = fmaf(w, hw, acc);
    }
    part[s][f] = acc;
    __syncthreads();
    if (s == 0) {
        float tot_v = bias[f];
        #pragma unroll
        for (int q = 0; q < 8; ++q) tot_v += part[q][f];
        int i = n * HID + f;
        if (EPI == 0)      OUT[i] = tot_v;
        else if (EPI == 1) OUT[i] = tot_v + fmaxf(RES[i], 0.f);
        else               OUT[i] = fmaxf(tot_v + fmaxf(RES[i], 0.f), 0.f);
    }
}

// ---------------- split-K GEMV: 1024-col tiles, f4 v-broadcast, zero-skip ------
// unroll 8 row-quads: up to 32 predicated 16B loads in flight per wave
// (~512 B/wave, ~4 KB/SIMD at 8 waves) to cover ~900cy HBM latency.
template<int R>
__global__ void __launch_bounds__(256) gemv_part_k(
    const float* __restrict__ v, const float* __restrict__ W,
    float* __restrict__ part, int cols)
{
    const int col0 = blockIdx.x * 1024 + threadIdx.x * 4;
    const int row0 = blockIdx.y * R;
    const f4* vq = reinterpret_cast<const f4*>(v + row0);
    const float* Wp = W + (size_t)row0 * cols + col0;
    f4 acc = {0.f, 0.f, 0.f, 0.f};
    #pragma unroll 8
    for (int rq = 0; rq < R / 4; ++rq) {
        f4 s4 = vq[rq];                       // uniform -> s_load_dwordx4
        const float* Wr = Wp + (size_t)(rq * 4) * cols;
        if (s4.x != 0.f) { f4 w = __builtin_nontemporal_load((const f4*)(Wr));            acc += s4.x * w; }
        if (s4.y != 0.f) { f4 w = __builtin_nontemporal_load((const f4*)(Wr + cols));     acc += s4.y * w; }
        if (s4.z != 0.f) { f4 w = __builtin_nontemporal_load((const f4*)(Wr + 2 * cols)); acc += s4.z * w; }
        if (s4.w != 0.f) { f4 w = __builtin_nontemporal_load((const f4*)(Wr + 3 * cols)); acc += s4.w * w; }
    }
    *reinterpret_cast<f4*>(part + (size_t)blockIdx.y * cols + col0) = acc;
}

// ---------------- 2-level split reduce: 64 cols/block, 4 split-groups ----------
template<int SPLITS>
__global__ void __launch_bounds__(256) reduce_bias_relu_k(
    const float* __restrict__ part, const float* __restrict__ b,
    float* __restrict__ y, int cols)
{
    __shared__ float red[256];
    const int t = threadIdx.x;
    const int jj = t & 63;
    const int g = t >> 6;
    const int j = blockIdx.x * 64 + jj;
    float acc = 0.f;
    #pragma unroll 4
    for (int s = g; s < SPLITS; s += 4)
        acc += part[(size_t)s * cols + j];
    red[t] = acc;
    __syncthreads();
    if (g == 0) {
        float tot = b[j] + red[jj] + red[64 + jj] + red[128 + jj] + red[192 + jj];
        y[j] = fmaxf(tot, 0.f);
    }
}

// ---------------- last GEMV: 256 cols, one col per thread, zero-skip ----------
template<int R>
__global__ void __launch_bounds__(256) gemv3_k(
    const float* __restrict__ v, const float* __restrict__ W,
    float* __restrict__ part)
{
    const int t = threadIdx.x;
    const int row0 = blockIdx.x * R;
    float acc = 0.f;
    #pragma unroll 8
    for (int r = 0; r < R; ++r) {
        float s = v[row0 + r];
        if (s != 0.f)
            acc = fmaf(s, __builtin_nontemporal_load(&W[(size_t)(row0 + r) * OUT_DIM + t]), acc);
    }
    part[blockIdx.x * OUT_DIM + t] = acc;
}

template<int SPLITS>
__global__ void __launch_bounds__(256) softmax_k(
    const float* __restrict__ part3, const float* __restrict__ b3,
    float* __restrict__ out)
{
    __shared__ float red[256];
    const int t = threadIdx.x;
    float acc = b3[t];
    #pragma unroll 8
    for (int s = 0; s < SPLITS; ++s) acc += part3[s * OUT_DIM + t];
    red[t] = acc;
    __syncthreads();
    for (int k = 128; k > 0; k >>= 1) {
        if (t < k) red[t] = fmaxf(red[t], red[t + k]);
        __syncthreads();
    }
    float m = red[0];
    __syncthreads();
    float e = expf(acc - m);
    red[t] = e;
    __syncthreads();
    for (int k = 128; k > 0; k >>= 1) {
        if (t < k) red[t] += red[t + k];
        __syncthreads();
    }
    out[t] = e / red[0];
}

extern "C" void kernel_launch(void* const* d_in, const int* in_sizes, int n_in,
                              void* d_out, int out_size, void* d_ws, size_t ws_size,
                              hipStream_t stream) {
    const float* x    = (const float*)d_in[0];
    const int*   ei   = (const int*)  d_in[1];   // [2, NE]
    const float* W_in = (const float*)d_in[2];
    const float* b_in = (const float*)d_in[3];
    const float* Wb   = (const float*)d_in[4];   // [3,2,32,32]
    const float* bb   = (const float*)d_in[5];   // [3,2,32]
    const float* W1   = (const float*)d_in[6];   // [32768,8192]
    const float* b1   = (const float*)d_in[7];
    const float* W2   = (const float*)d_in[8];   // [8192,4096]
    const float* b2   = (const float*)d_in[9];
    const float* W3   = (const float*)d_in[10];  // [4096,256]
    const float* b3   = (const float*)d_in[11];
    float* out = (float*)d_out;

    const int* row = ei;
    const int* col = ei + NE;

    float* ws    = (float*)d_ws;
    float* deg   = ws;                   // 1024
    int*   off   = (int*)(deg + NN);     // 1024
    int*   nrow  = off + NN;             // 8192
    float* nw    = (float*)(nrow + NE);  // 8192
    float* H1    = nw + NE;              // 32768
    float* H2    = H1 + FDIM;            // 32768
    float* H3    = H2 + FDIM;            // 32768
    float* T     = H3 + FDIM;            // 32768
    float* v     = T + FDIM;             // 32768
    float* part1 = v + FDIM;             // 256*8192 = 2M
    float* y1    = part1 + 256 * F4;     // 8192
    float* part2 = y1 + F4;              // 256*4096 = 1M
    float* y2    = part2 + 256 * F8;     // 4096
    float* part3 = y2 + F8;              // 128*256

    // ---- CSR build: ONE kernel ----
    csr_k<<<1, 1024, 0, stream>>>(row, col, deg, off, nrow, nw);

    // ---- 7 gather-form convs ----
    conv_k<IN_DIM, 0, 0><<<NN, 256, 0, stream>>>(x,  nullptr, W_in, b_in, deg, off, nrow, nw, H1);
    conv_k<HID, 1, 0><<<NN, 256, 0, stream>>>(H1, nullptr, Wb + 0*HID*HID, bb + 0*HID, deg, off, nrow, nw, T);
    conv_k<HID, 1, 1><<<NN, 256, 0, stream>>>(T,  H1,      Wb + 1*HID*HID, bb + 1*HID, deg, off, nrow, nw, H2);
    conv_k<HID, 1, 0><<<NN, 256, 0, stream>>>(H2, nullptr, Wb + 2*HID*HID, bb + 2*HID, deg, off, nrow, nw, T);
    conv_k<HID, 1, 1><<<NN, 256, 0, stream>>>(T,  H2,      Wb + 3*HID*HID, bb + 3*HID, deg, off, nrow, nw, H3);
    conv_k<HID, 1, 0><<<NN, 256, 0, stream>>>(H3, nullptr, Wb + 4*HID*HID, bb + 4*HID, deg, off, nrow, nw, T);
    conv_k<HID, 1, 2><<<NN, 256, 0, stream>>>(T,  H3,      Wb + 5*HID*HID, bb + 5*HID, deg, off, nrow, nw, v);

    // ---- MLP head (exact R5 grids; only the unroll depth changed) ----
    {   // y1 = relu(v @ W1 + b1): R=128 -> 256 splits, grid (8,256)
        dim3 g(F4 / 1024, FDIM / 128);
        gemv_part_k<128><<<g, 256, 0, stream>>>(v, W1, part1, F4);
        reduce_bias_relu_k<256><<<F4 / 64, 256, 0, stream>>>(part1, b1, y1, F4);
    }
    {   // y2 = relu(y1 @ W2 + b2): R=32 -> 256 splits, grid (4,256)
        dim3 g(F8 / 1024, F4 / 32);
        gemv_part_k<32><<<g, 256, 0, stream>>>(y1, W2, part2, F8);
        reduce_bias_relu_k<256><<<F8 / 64, 256, 0, stream>>>(part2, b2, y2, F8);
    }
    {   // y3: 128 splits of 32 rows; softmax fuses reduce+bias
        gemv3_k<32><<<F8 / 32, 256, 0, stream>>>(y2, W3, part3);
        softmax_k<128><<<1, 256, 0, stream>>>(part3, b3, out);
    }
}

// Round 10
// 235.290 us; speedup vs baseline: 1.1407x; 1.1407x over previous
//
#include <hip/hip_runtime.h>

#define NN      1024      // num nodes
#define IN_DIM  16
#define HID     32
#define OUT_DIM 256
#define NE      8192      // edges (without self loops)
#define FDIM    (NN*HID)  // 32768
#define F4      (FDIM/4)  // 8192
#define F8      (FDIM/8)  // 4096
#define MAXNB   48        // staged rows per node (self + neighbors)

typedef float f4 __attribute__((ext_vector_type(4)));

// ---------------- fused CSR build: one block, all in LDS ----------------
__global__ void __launch_bounds__(1024) csr_k(
    const int* __restrict__ row, const int* __restrict__ col,
    float* __restrict__ deg_g, int* __restrict__ off_g,
    int* __restrict__ nrow, float* __restrict__ nw)
{
    __shared__ float degs[NN];
    __shared__ int   curs[NN];
    __shared__ int   scan[NN];
    const int t = threadIdx.x;
    degs[t] = 1.f;                       // self loop
    __syncthreads();
    for (int e = t; e < NE; e += 1024) atomicAdd(&degs[col[e]], 1.f);
    __syncthreads();
    int c = (int)degs[t] - 1;            // in-edges excluding self loop
    scan[t] = c;
    __syncthreads();
    for (int d = 1; d < 1024; d <<= 1) {
        int v = (t >= d) ? scan[t - d] : 0;
        __syncthreads();
        scan[t] += v;
        __syncthreads();
    }
    int excl = scan[t] - c;
    curs[t] = excl;
    off_g[t] = excl;
    deg_g[t] = degs[t];
    __syncthreads();
    for (int e = t; e < NE; e += 1024) {
        int r = row[e], cc = col[e];
        int slot = atomicAdd(&curs[cc], 1);
        nrow[slot] = r;
        nw[slot] = rsqrtf(degs[r] * degs[cc]);
    }
}

// ---------------- gather-form GCN conv: one block per node, LDS-staged rows ----
// EPI: 0 -> OUT = tot ; 1 -> OUT = tot + relu(RES) ; 2 -> OUT = relu(tot + relu(RES))
template<int K, int RELU_IN, int EPI>
__global__ void __launch_bounds__(256) conv_k(
    const float* __restrict__ IN, const float* __restrict__ RES,
    const float* __restrict__ W, const float* __restrict__ bias,
    const float* __restrict__ deg, const int* __restrict__ off,
    const int* __restrict__ nrow, const float* __restrict__ nw,
    float* __restrict__ OUT)
{
    const int n = blockIdx.x;
    const int tid = threadIdx.x;
    const int s = tid >> 5, f = tid & 31;
    __shared__ float rows[MAXNB][K + 4];
    __shared__ float part[8][33];
    const int base = off[n];
    const int cnt = (int)deg[n] - 1;         // neighbors excluding self
    const int tot = cnt + 1;
    const int stg = tot < MAXNB ? tot : MAXNB;
    const int vecs = K / 4;
    for (int idx = tid; idx < stg * vecs; idx += 256) {
        int j = idx / vecs, q = idx - j * vecs;
        int r = (j == 0) ? n : nrow[base + j - 1];
        float4 val = *reinterpret_cast<const float4*>(IN + r * K + q * 4);
        if (RELU_IN) {
            val.x = fmaxf(val.x, 0.f); val.y = fmaxf(val.y, 0.f);
            val.z = fmaxf(val.z, 0.f); val.w = fmaxf(val.w, 0.f);
        }
        rows[j][q * 4 + 0] = val.x; rows[j][q * 4 + 1] = val.y;
        rows[j][q * 4 + 2] = val.z; rows[j][q * 4 + 3] = val.w;
    }
    __syncthreads();
    float acc = 0.f;
    for (int j = s; j < tot; j += 8) {
        float w = (j == 0) ? (1.0f / deg[n]) : nw[base + j - 1];
        float hw = 0.f;
        if (j < MAXNB) {
            #pragma unroll
            for (int k = 0; k < K; ++k)
                hw = fmaf(rows[j][k], W[k * HID + f], hw);
        } else {
            const float* inr = IN + nrow[base + j - 1] * K;
            #pragma unroll
            for (int k = 0; k < K; ++k) {
                float t = inr[k];
                if (RELU_IN) t = fmaxf(t, 0.f);
                hw = fmaf(t, W[k * HID + f], hw);
            }
        }
        acc = fmaf(w, hw, acc);
    }
    part[s][f] = acc;
    __syncthreads();
    if (s == 0) {
        float tot_v = bias[f];
        #pragma unroll
        for (int q = 0; q < 8; ++q) tot_v += part[q][f];
        int i = n * HID + f;
        if (EPI == 0)      OUT[i] = tot_v;
        else if (EPI == 1) OUT[i] = tot_v + fmaxf(RES[i], 0.f);
        else               OUT[i] = fmaxf(tot_v + fmaxf(RES[i], 0.f), 0.f);
    }
}

// ---------------- split-K GEMV: float4 v-broadcast + zero-skip + nt W stream --
template<int R>
__global__ void __launch_bounds__(256) gemv_part_k(
    const float* __restrict__ v, const float* __restrict__ W,
    float* __restrict__ part, int cols)
{
    const int col0 = blockIdx.x * 1024 + threadIdx.x * 4;
    const int row0 = blockIdx.y * R;
    const f4* vq = reinterpret_cast<const f4*>(v + row0);
    const float* Wp = W + (size_t)row0 * cols + col0;
    f4 acc = {0.f, 0.f, 0.f, 0.f};
    #pragma unroll 4
    for (int rq = 0; rq < R / 4; ++rq) {
        f4 s4 = vq[rq];                       // uniform -> s_load_dwordx4
        const float* Wr = Wp + (size_t)(rq * 4) * cols;
        if (s4.x != 0.f) { f4 w = __builtin_nontemporal_load((const f4*)(Wr));            acc += s4.x * w; }
        if (s4.y != 0.f) { f4 w = __builtin_nontemporal_load((const f4*)(Wr + cols));     acc += s4.y * w; }
        if (s4.z != 0.f) { f4 w = __builtin_nontemporal_load((const f4*)(Wr + 2 * cols)); acc += s4.z * w; }
        if (s4.w != 0.f) { f4 w = __builtin_nontemporal_load((const f4*)(Wr + 3 * cols)); acc += s4.w * w; }
    }
    *reinterpret_cast<f4*>(part + (size_t)blockIdx.y * cols + col0) = acc;
}

// ---------------- 2-level split reduce: 64 cols/block, 4 split-groups ----------
template<int SPLITS>
__global__ void __launch_bounds__(256) reduce_bias_relu_k(
    const float* __restrict__ part, const float* __restrict__ b,
    float* __restrict__ y, int cols)
{
    __shared__ float red[256];
    const int t = threadIdx.x;
    const int jj = t & 63;
    const int g = t >> 6;
    const int j = blockIdx.x * 64 + jj;
    float acc = 0.f;
    #pragma unroll 4
    for (int s = g; s < SPLITS; s += 4)
        acc += part[(size_t)s * cols + j];
    red[t] = acc;
    __syncthreads();
    if (g == 0) {
        float tot = b[j] + red[jj] + red[64 + jj] + red[128 + jj] + red[192 + jj];
        y[j] = fmaxf(tot, 0.f);
    }
}

// ---------------- last GEMV: 256 cols, one col per thread, zero-skip ----------
template<int R>
__global__ void __launch_bounds__(256) gemv3_k(
    const float* __restrict__ v, const float* __restrict__ W,
    float* __restrict__ part)
{
    const int t = threadIdx.x;
    const int row0 = blockIdx.x * R;
    float acc = 0.f;
    #pragma unroll 8
    for (int r = 0; r < R; ++r) {
        float s = v[row0 + r];
        if (s != 0.f)
            acc = fmaf(s, __builtin_nontemporal_load(&W[(size_t)(row0 + r) * OUT_DIM + t]), acc);
    }
    part[blockIdx.x * OUT_DIM + t] = acc;
}

template<int SPLITS>
__global__ void __launch_bounds__(256) softmax_k(
    const float* __restrict__ part3, const float* __restrict__ b3,
    float* __restrict__ out)
{
    __shared__ float red[256];
    const int t = threadIdx.x;
    float acc = b3[t];
    #pragma unroll 8
    for (int s = 0; s < SPLITS; ++s) acc += part3[s * OUT_DIM + t];
    red[t] = acc;
    __syncthreads();
    for (int k = 128; k > 0; k >>= 1) {
        if (t < k) red[t] = fmaxf(red[t], red[t + k]);
        __syncthreads();
    }
    float m = red[0];
    __syncthreads();
    float e = expf(acc - m);
    red[t] = e;
    __syncthreads();
    for (int k = 128; k > 0; k >>= 1) {
        if (t < k) red[t] += red[t + k];
        __syncthreads();
    }
    out[t] = e / red[0];
}

extern "C" void kernel_launch(void* const* d_in, const int* in_sizes, int n_in,
                              void* d_out, int out_size, void* d_ws, size_t ws_size,
                              hipStream_t stream) {
    const float* x    = (const float*)d_in[0];
    const int*   ei   = (const int*)  d_in[1];   // [2, NE]
    const float* W_in = (const float*)d_in[2];
    const float* b_in = (const float*)d_in[3];
    const float* Wb   = (const float*)d_in[4];   // [3,2,32,32]
    const float* bb   = (const float*)d_in[5];   // [3,2,32]
    const float* W1   = (const float*)d_in[6];   // [32768,8192]
    const float* b1   = (const float*)d_in[7];
    const float* W2   = (const float*)d_in[8];   // [8192,4096]
    const float* b2   = (const float*)d_in[9];
    const float* W3   = (const float*)d_in[10];  // [4096,256]
    const float* b3   = (const float*)d_in[11];
    float* out = (float*)d_out;

    const int* row = ei;
    const int* col = ei + NE;

    float* ws    = (float*)d_ws;
    float* deg   = ws;                   // 1024
    int*   off   = (int*)(deg + NN);     // 1024
    int*   nrow  = off + NN;             // 8192
    float* nw    = (float*)(nrow + NE);  // 8192
    float* H1    = nw + NE;              // 32768
    float* H2    = H1 + FDIM;            // 32768
    float* H3    = H2 + FDIM;            // 32768
    float* T     = H3 + FDIM;            // 32768
    float* v     = T + FDIM;             // 32768
    float* part1 = v + FDIM;             // 256*8192 = 2M
    float* y1    = part1 + 256 * F4;     // 8192
    float* part2 = y1 + F4;              // 256*4096 = 1M
    float* y2    = part2 + 256 * F8;     // 4096
    float* part3 = y2 + F8;              // 128*256

    // ---- CSR build: ONE kernel ----
    csr_k<<<1, 1024, 0, stream>>>(row, col, deg, off, nrow, nw);

    // ---- 7 gather-form convs ----
    conv_k<IN_DIM, 0, 0><<<NN, 256, 0, stream>>>(x,  nullptr, W_in, b_in, deg, off, nrow, nw, H1);
    conv_k<HID, 1, 0><<<NN, 256, 0, stream>>>(H1, nullptr, Wb + 0*HID*HID, bb + 0*HID, deg, off, nrow, nw, T);
    conv_k<HID, 1, 1><<<NN, 256, 0, stream>>>(T,  H1,      Wb + 1*HID*HID, bb + 1*HID, deg, off, nrow, nw, H2);
    conv_k<HID, 1, 0><<<NN, 256, 0, stream>>>(H2, nullptr, Wb + 2*HID*HID, bb + 2*HID, deg, off, nrow, nw, T);
    conv_k<HID, 1, 1><<<NN, 256, 0, stream>>>(T,  H2,      Wb + 3*HID*HID, bb + 3*HID, deg, off, nrow, nw, H3);
    conv_k<HID, 1, 0><<<NN, 256, 0, stream>>>(H3, nullptr, Wb + 4*HID*HID, bb + 4*HID, deg, off, nrow, nw, T);
    conv_k<HID, 1, 2><<<NN, 256, 0, stream>>>(T,  H3,      Wb + 5*HID*HID, bb + 5*HID, deg, off, nrow, nw, v);

    // ---- MLP head ----
    {   // y1 = relu(v @ W1 + b1): R=128 -> 256 splits, 2048 blocks
        dim3 g(F4 / 1024, FDIM / 128);
        gemv_part_k<128><<<g, 256, 0, stream>>>(v, W1, part1, F4);
        reduce_bias_relu_k<256><<<F4 / 64, 256, 0, stream>>>(part1, b1, y1, F4);
    }
    {   // y2 = relu(y1 @ W2 + b2): R=32 -> 256 splits, 1024 blocks
        dim3 g(F8 / 1024, F4 / 32);
        gemv_part_k<32><<<g, 256, 0, stream>>>(y1, W2, part2, F8);
        reduce_bias_relu_k<256><<<F8 / 64, 256, 0, stream>>>(part2, b2, y2, F8);
    }
    {   // y3: 128 splits of 32 rows; softmax fuses reduce+bias
        gemv3_k<32><<<F8 / 32, 256, 0, stream>>>(y2, W3, part3);
        softmax_k<128><<<1, 256, 0, stream>>>(part3, b3, out);
    }
}